// Round 1
// 68.890 us; speedup vs baseline: 1.0163x; 1.0163x over previous
//
#include <hip/hip_runtime.h>
#include <math.h>

// PeakSense: out[b,p] = sum_i exp(-0.5*(mz[b,i]-mu[p])^2 * exp(-lv[p])) * iv[b,i],
// terms with arg < -10 dropped.
//
// Latency-oriented revision of the 70us kernel:
//  - SUB=4 threads per peak, 64 peaks/block, pgroups=4 -> 512 blocks = 2
//    blocks/CU so independent blocks overlap each other's phases.
//  - Staging loads issued as float4 into registers FIRST; the per-peak
//    binary search then runs on the GLOBAL row (L2/L3-resident) while those
//    loads are in flight; LDS writes land after (issue-early/write-late).
//  - Binary search split across sub pairs: even subs find the lower bound,
//    odd subs the upper bound, exchanged with one shfl_xor -> 12 dependent
//    loads on the critical path instead of 24.
//  - Exact per-term threshold test kept -> bit-identical accumulation set.

#define BLOCK 256
#define SUB 4
#define PPB (BLOCK / SUB)   // 64 peaks per block
#define MAXL 4096
#define THRESH -10.0f

__global__ __launch_bounds__(BLOCK) void peaksense_kernel(
    const float* __restrict__ mu,
    const float* __restrict__ lv,
    const float* __restrict__ masses,
    const float* __restrict__ inten,
    float* __restrict__ out,
    int B, int L, int N)
{
    __shared__ float2 s[MAXL];   // interleaved {mass, intensity}, 32 KB

    const int pg = blockIdx.x;   // peak group
    const int b  = blockIdx.y;
    const int t  = threadIdx.x;

    const float* __restrict__ mrow = masses + (size_t)b * L;
    const float* __restrict__ irow = inten  + (size_t)b * L;

    const bool fast = (L == MAXL);   // L=4096 path: statically unrolled staging

    // ---- phase 1: issue staging loads (fast path: into registers, so the
    // global binary search below overlaps the in-flight loads) ----
    float4 m0, m1, m2, m3, i0, i1, i2, i3;
    if (fast) {
        const float4* __restrict__ mrow4 = reinterpret_cast<const float4*>(mrow);
        const float4* __restrict__ irow4 = reinterpret_cast<const float4*>(irow);
        m0 = mrow4[t];             i0 = irow4[t];
        m1 = mrow4[t +   BLOCK];   i1 = irow4[t +   BLOCK];
        m2 = mrow4[t + 2*BLOCK];   i2 = irow4[t + 2*BLOCK];
        m3 = mrow4[t + 3*BLOCK];   i3 = irow4[t + 3*BLOCK];
    } else {
        for (int i = t; i < L; i += BLOCK)
            s[i] = make_float2(mrow[i], irow[i]);
    }

    // ---- per-peak parameters ----
    const int  lp     = t >> 2;        // local peak 0..63
    const int  sub    = t & 3;         // quarter-range selector
    const int  p      = pg * PPB + lp;
    const bool active = (p < N);
    const int  pc     = active ? p : (N - 1);   // clamp for safe loads

    const float mu_p = mu[pc];                 // 4 lanes broadcast-share
    const float lvp  = lv[pc];
    const float inv  = __expf(-lvp);           // 1/sigma^2
    const float nh   = -0.5f * inv;
    // arg >= -10  <=>  |d| <= sqrt(20)*sigma; margin covers fp rounding, the
    // exact per-term test below keeps the result bit-for-bit safe.
    const float r    = sqrtf(20.0f / inv) * 1.00001f + 1e-3f;
    const float tlo  = mu_p - r;
    const float thi  = mu_p + r;

    // ---- split binary search on the GLOBAL row (overlaps staging loads):
    // even subs: first i with m >= tlo; odd subs: first i with m > thi ----
    const bool  isHi   = sub & 1;
    const float target = isHi ? thi : tlo;
    int lo = 0, hi = L;
    while (lo < hi) {
        const int   mid = (lo + hi) >> 1;
        const float v   = mrow[mid];
        const bool  go  = isHi ? (v <= target) : (v < target);
        if (go) lo = mid + 1; else hi = mid;
    }
    const int other = __shfl_xor(lo, 1);
    const int start = isHi ? other : lo;
    const int end   = isHi ? lo    : other;

    // ---- phase 2: LDS writes (fast path), then the one barrier ----
    if (fast) {
        float4* __restrict__ s4 = reinterpret_cast<float4*>(s);
        s4[2*t]                   = make_float4(m0.x, i0.x, m0.y, i0.y);
        s4[2*t + 1]               = make_float4(m0.z, i0.z, m0.w, i0.w);
        s4[2*(t +   BLOCK)]       = make_float4(m1.x, i1.x, m1.y, i1.y);
        s4[2*(t +   BLOCK) + 1]   = make_float4(m1.z, i1.z, m1.w, i1.w);
        s4[2*(t + 2*BLOCK)]       = make_float4(m2.x, i2.x, m2.y, i2.y);
        s4[2*(t + 2*BLOCK) + 1]   = make_float4(m2.z, i2.z, m2.w, i2.w);
        s4[2*(t + 3*BLOCK)]       = make_float4(m3.x, i3.x, m3.y, i3.y);
        s4[2*(t + 3*BLOCK) + 1]   = make_float4(m3.z, i3.z, m3.w, i3.w);
    }
    __syncthreads();               // only barrier; no thread returned above

    // ---- main loop: ~18 terms per thread ----
    float acc = 0.0f;
    for (int i = start + sub; i < end; i += SUB) {
        const float2 v  = s[i];                // ds_read_b64
        const float d   = v.x - mu_p;
        const float arg = d * d * nh;
        if (arg >= THRESH)
            acc += __expf(arg) * v.y;
    }
    acc += __shfl_xor(acc, 1);                 // merge quarter pair
    acc += __shfl_xor(acc, 2);                 // merge halves (same wave)
    if (sub == 0 && active)
        out[(size_t)b * N + p] = acc;          // exactly-once '=' write
}

extern "C" void kernel_launch(void* const* d_in, const int* in_sizes, int n_in,
                              void* d_out, int out_size, void* d_ws, size_t ws_size,
                              hipStream_t stream) {
    const float* mu     = (const float*)d_in[0];
    const float* lv     = (const float*)d_in[1];
    const float* masses = (const float*)d_in[2];
    const float* inten  = (const float*)d_in[3];
    float* out = (float*)d_out;

    const int N = in_sizes[0];
    const int B = out_size / N;
    const int L = in_sizes[2] / B;

    const int pgroups = (N + PPB - 1) / PPB;   // 4 for N=256
    dim3 grid(pgroups, B);                     // 512 blocks -> 2 per CU
    peaksense_kernel<<<grid, BLOCK, 0, stream>>>(mu, lv, masses, inten, out, B, L, N);
}